// Round 8
// baseline (1085.231 us; speedup 1.0000x reference)
//
#include <hip/hip_runtime.h>

#define NBLKA 2048

__device__ __forceinline__ unsigned encf(float x) {
    unsigned u = __float_as_uint(x);
    return (u & 0x80000000u) ? ~u : (u | 0x80000000u);
}
__device__ __forceinline__ float decf(unsigned u) {
    u = (u & 0x80000000u) ? (u & 0x7FFFFFFFu) : ~u;
    return __uint_as_float(u);
}
__device__ __forceinline__ unsigned bf16rne(float f) {
    unsigned u = __float_as_uint(f);
    return (u + 0x7FFFu + ((u >> 16) & 1u)) >> 16;
}

// ============ CSR build: 512-node buckets, deterministic matrix scan ============

// pass A: per-(bucket, block) histogram, bucket = dst >> bshift (<=512 buckets)
__global__ __launch_bounds__(256) void passA_k(const int* __restrict__ dst, int E,
                                               int* __restrict__ cntMat, int bshift,
                                               int nblk, int nb2) {
    __shared__ int hist[512];
    hist[threadIdx.x] = 0; hist[threadIdx.x + 256] = 0;
    __syncthreads();
    int base = blockIdx.x * 4096;
#pragma unroll
    for (int r = 0; r < 16; r++) {
        int i = base + threadIdx.x + r * 256;
        if (i < E) atomicAdd(&hist[dst[i] >> bshift], 1);
    }
    __syncthreads();
    for (int bk = threadIdx.x; bk < nb2; bk += 256)
        cntMat[bk * nblk + blockIdx.x] = hist[bk];
}

__global__ void scanA_k(int* __restrict__ data, int total, int* __restrict__ chunkTot) {
    __shared__ int sd[256];
    int tid = threadIdx.x;
    int base = blockIdx.x * 2048 + tid * 8;
    int v[8]; int s = 0;
#pragma unroll
    for (int r = 0; r < 8; r++) {
        int idx = base + r;
        int x = (idx < total) ? data[idx] : 0;
        s += x; v[r] = s;
    }
    sd[tid] = s; __syncthreads();
    for (int off = 1; off < 256; off <<= 1) {
        int x = (tid >= off) ? sd[tid - off] : 0;
        __syncthreads();
        sd[tid] += x;
        __syncthreads();
    }
    int prev = (tid > 0) ? sd[tid - 1] : 0;
#pragma unroll
    for (int r = 0; r < 8; r++) {
        int idx = base + r;
        if (idx < total) data[idx] = v[r] + prev;
    }
    if (tid == 255) chunkTot[blockIdx.x] = sd[255];
}

__global__ void scanB_k(const int* __restrict__ chunkTot, int nchunk, int* __restrict__ chunkOff) {
    __shared__ int sd[256];
    int tid = threadIdx.x;
    int v = (tid < nchunk) ? chunkTot[tid] : 0;
    sd[tid] = v; __syncthreads();
    for (int off = 1; off < 256; off <<= 1) {
        int x = (tid >= off) ? sd[tid - off] : 0;
        __syncthreads();
        sd[tid] += x;
        __syncthreads();
    }
    if (tid < nchunk) chunkOff[tid] = sd[tid] - v;
}

__global__ void scanC2_k(int* __restrict__ data, int total, const int* __restrict__ chunkOff) {
    int off = chunkOff[blockIdx.x];
    int base = blockIdx.x * 2048 + threadIdx.x * 8;
#pragma unroll
    for (int r = 0; r < 8; r++) {
        int idx = base + r;
        if (idx < total) data[idx] += off;
    }
}

// pass B: LDS counting sort of 4096 edges into 512 bucket-grouped segments
__global__ __launch_bounds__(256) void passB_k(const int* __restrict__ ei,
                                               const int* __restrict__ ety, int E,
                                               const int* __restrict__ cntScan,
                                               unsigned* __restrict__ binned,
                                               int bshift, int sBits, int nblk, int nb2) {
    __shared__ unsigned stage[4096];
    __shared__ unsigned short bkid[4096];
    __shared__ int hist[512], sd[256], cursor[512], rebase[512];
    int tid = threadIdx.x;
    int base = blockIdx.x * 4096;
    hist[tid] = 0; hist[tid + 256] = 0;
    __syncthreads();

    unsigned ent[16];
    int bk[16];
    int lowmask = (1 << bshift) - 1;
    int dshift = sBits + 1;
#pragma unroll
    for (int r = 0; r < 16; r++) {
        int i = base + tid + r * 256;
        if (i < E) {
            int s = ei[i];
            int d = ei[E + i];
            int t = ety[i];
            ent[r] = ((unsigned)(d & lowmask) << dshift) | ((unsigned)t << sBits) | (unsigned)s;
            bk[r] = d >> bshift;
            atomicAdd(&hist[bk[r]], 1);
        } else bk[r] = -1;
    }
    __syncthreads();

    int v0 = hist[2 * tid], v1 = hist[2 * tid + 1];
    int sum2 = v0 + v1;
    sd[tid] = sum2; __syncthreads();
    for (int off = 1; off < 256; off <<= 1) {
        int x = (tid >= off) ? sd[tid - off] : 0;
        __syncthreads();
        sd[tid] += x;
        __syncthreads();
    }
    int exclPair = sd[tid] - sum2;
    __syncthreads();
    cursor[2 * tid] = exclPair;
    cursor[2 * tid + 1] = exclPair + v0;
    int b0 = 2 * tid, b1 = 2 * tid + 1;
    rebase[b0] = (b0 < nb2 && v0 > 0) ? (cntScan[b0 * nblk + blockIdx.x] - v0) - exclPair : 0;
    rebase[b1] = (b1 < nb2 && v1 > 0) ? (cntScan[b1 * nblk + blockIdx.x] - v1) - (exclPair + v0) : 0;
    __syncthreads();

#pragma unroll
    for (int r = 0; r < 16; r++) {
        if (bk[r] >= 0) {
            int p = atomicAdd(&cursor[bk[r]], 1);
            stage[p] = ent[r];
            bkid[p] = (unsigned short)bk[r];
        }
    }
    __syncthreads();

    int cnt = E - base; if (cnt > 4096) cnt = 4096;
    for (int i = tid; i < cnt; i += 256)
        binned[rebase[bkid[i]] + i] = stage[i];
}

// pass C: one block per 512-node bucket; single phase; fused rowptr;
// direct global scatter into the block's private [s,e) window (L2-local).
__global__ __launch_bounds__(256) void passC_k(const unsigned* __restrict__ binned,
                                               const int* __restrict__ cntScan,
                                               int nblk, int* __restrict__ rowptr,
                                               unsigned* __restrict__ sorted,
                                               int N, int E, int bshift, int sBits,
                                               int nb2) {
    __shared__ int hist[512], cursor[512], sd[256];
    int tid = threadIdx.x;
    int b = blockIdx.x;
    int s = (b == 0) ? 0 : cntScan[b * nblk - 1];
    int e = cntScan[(b + 1) * nblk - 1];
    int nodeBase = b << bshift;
    int dshift = sBits + 1;

    hist[tid] = 0; hist[tid + 256] = 0;
    __syncthreads();
    for (int i = s + tid; i < e; i += 256)
        atomicAdd(&hist[(int)(binned[i] >> dshift)], 1);
    __syncthreads();

    int v0 = hist[2 * tid], v1 = hist[2 * tid + 1];
    int sum2 = v0 + v1;
    sd[tid] = sum2; __syncthreads();
    for (int off = 1; off < 256; off <<= 1) {
        int x = (tid >= off) ? sd[tid - off] : 0;
        __syncthreads();
        sd[tid] += x;
        __syncthreads();
    }
    int exclPair = sd[tid] - sum2;
    __syncthreads();
    cursor[2 * tid] = exclPair;
    cursor[2 * tid + 1] = exclPair + v0;
    int n0 = nodeBase + 2 * tid, n1 = nodeBase + 2 * tid + 1;
    if (n0 < N) rowptr[n0] = s + exclPair;
    if (n1 < N) rowptr[n1] = s + exclPair + v0;
    __syncthreads();

    for (int i = s + tid; i < e; i += 256) {
        unsigned en = binned[i];
        int ln = (int)(en >> dshift);
        int p = atomicAdd(&cursor[ln], 1);
        sorted[s + p] = en;
    }
    if (b == nb2 - 1 && tid == 0) rowptr[N] = E;
}

__global__ void initpool_k(unsigned* __restrict__ maxb, float* __restrict__ sumb, int n) {
    int i = blockIdx.x * blockDim.x + threadIdx.x;
    if (i < n) { maxb[i] = 0x007FFFFFu; sumb[i] = 0.f; }
}

// copy x -> packed bf16 pairs in P; set sentinel rows of P and Q
__global__ void copyx_k(const float* __restrict__ x, unsigned* __restrict__ P,
                        unsigned* __restrict__ Q, int N) {
    int i = blockIdx.x * 256 + threadIdx.x;
    int tot = N * 16;
    if (i < tot) {
        float2 v = ((const float2*)x)[i];
        P[i] = bf16rne(v.x) | (bf16rne(v.y) << 16);
    }
    if (i < 16) {
        unsigned sp = bf16rne(-1e30f) | (bf16rne(-1e30f) << 16);
        P[tot + i] = sp;
        Q[tot + i] = sp;
    }
}

// ---------- layer A: 16 ch-lanes x 2 edge slots, bf16 h, bounded tail ----------
__global__ __launch_bounds__(256) void layerA_k(
    const unsigned* __restrict__ hin, const int* __restrict__ rowptr,
    const unsigned* __restrict__ sorted, const float* __restrict__ emb,
    const float* __restrict__ W1, const float* __restrict__ b1,
    float* __restrict__ tout, float* __restrict__ partial, int Nn, int sBits,
    unsigned sentw)
{
    float2* tout2 = (float2*)tout;
    int tid = threadIdx.x;
    int gl = tid & 31;
    int c = gl & 15;            // channel-pair index
    int slot = gl >> 4;         // edge parity / k-half
    int grp = tid >> 5;
    unsigned smask = (1u << sBits) - 1u;

    float2 w1c[16];
#pragma unroll
    for (int kk = 0; kk < 16; kk++)
        w1c[kk] = *(const float2*)&W1[(16 * slot + kk) * 32 + 2 * c];
    float2 b1p = *(const float2*)&b1[2 * c];
    float2 e0p = *(const float2*)&emb[2 * c];
    float2 e1p = *(const float2*)&emb[32 + 2 * c];

    __shared__ float zl[8][32];
    __shared__ float ls[8][32], lq[8][32];

    float2 bsum = {0.f, 0.f}, bsq = {0.f, 0.f};

    int gid0 = (blockIdx.x * 256 + tid) >> 5;
    int nG = (gridDim.x * 256) >> 5;

#define EDGE(p)                                                         \
    {                                                                   \
        unsigned s_ = (p) & smask;                                      \
        unsigned w_ = hin[s_ * 16u + (unsigned)c];                      \
        float hx_ = __uint_as_float(w_ << 16);                          \
        float hy_ = __uint_as_float(w_ & 0xFFFF0000u);                  \
        bool t1_ = (((p) >> sBits) & 1u) != 0u;                         \
        float evx_ = t1_ ? e1p.x : e0p.x;                               \
        float evy_ = t1_ ? e1p.y : e0p.y;                               \
        accx += fmaxf(hx_ + evx_, 0.f);                                 \
        accy += fmaxf(hy_ + evy_, 0.f);                                 \
    }

    for (int n = gid0; n < Nn; n += nG) {
        int es = rowptr[n], ee = rowptr[n + 1];
        float accx = 0.f, accy = 0.f;
        int e0 = es;
        for (; e0 + 32 <= ee; e0 += 32) {           // full chunks (rare)
            unsigned pv = sorted[e0 + gl];
#pragma unroll
            for (int kk = 0; kk < 16; kk++) {
                unsigned p = (unsigned)__shfl((int)pv, 2 * kk + slot, 32);
                EDGE(p)
            }
        }
        int r = ee - e0;                             // 0..31 remainder
        if (r > 0) {
            unsigned pv = (gl < r) ? sorted[e0 + gl] : sentw;
            int half = (r + 1) >> 1;                 // group-uniform trip
#pragma unroll 4
            for (int kk = 0; kk < half; kk++) {
                unsigned p = (unsigned)__shfl((int)pv, 2 * kk + slot, 32);
                EDGE(p)
            }
        }
        accx += __shfl_xor(accx, 16);
        accy += __shfl_xor(accy, 16);
        unsigned wn = hin[(unsigned)n * 16u + (unsigned)c];
        accx += __uint_as_float(wn << 16);
        accy += __uint_as_float(wn & 0xFFFF0000u);

        if (slot == 0) { zl[grp][2 * c] = accx; zl[grp][2 * c + 1] = accy; }
        float tx = 0.f, ty = 0.f;
#pragma unroll
        for (int kk = 0; kk < 16; kk++) {
            float zk = zl[grp][16 * slot + kk];
            tx = fmaf(zk, w1c[kk].x, tx);
            ty = fmaf(zk, w1c[kk].y, ty);
        }
        tx += __shfl_xor(tx, 16);
        ty += __shfl_xor(ty, 16);
        tx += b1p.x; ty += b1p.y;
        if (slot == 0) { float2 tp; tp.x = tx; tp.y = ty; tout2[(unsigned)n * 16u + (unsigned)c] = tp; }
        bsum.x += tx; bsum.y += ty;
        bsq.x = fmaf(tx, tx, bsq.x);
        bsq.y = fmaf(ty, ty, bsq.y);
    }
#undef EDGE

    if (slot == 0) {
        ls[grp][2 * c] = bsum.x; ls[grp][2 * c + 1] = bsum.y;
        lq[grp][2 * c] = bsq.x;  lq[grp][2 * c + 1] = bsq.y;
    }
    __syncthreads();
    if (tid < 32) {
        float s = 0.f, q = 0.f;
#pragma unroll
        for (int r = 0; r < 8; r++) { s += ls[r][tid]; q += lq[r][tid]; }
        partial[blockIdx.x * 64 + tid] = s;
        partial[blockIdx.x * 64 + 32 + tid] = q;
    }
}

// ---------- BN stat reduce, two-stage parallel ----------
__global__ __launch_bounds__(256) void bnred1_k(const float* __restrict__ partial,
                                                float* __restrict__ partial2) {
    __shared__ float sd[4][64];
    int tid = threadIdx.x;
    int c = tid & 63, q = tid >> 6;
    int rowBase = blockIdx.x * 32 + q * 8;
    float s = 0.f;
#pragma unroll
    for (int r = 0; r < 8; r++) s += partial[(rowBase + r) * 64 + c];
    sd[q][c] = s;
    __syncthreads();
    if (q == 0) partial2[blockIdx.x * 64 + c] = sd[0][c] + sd[1][c] + sd[2][c] + sd[3][c];
}

__global__ __launch_bounds__(256) void bnred2_k(const float* __restrict__ partial2,
                                                const float* __restrict__ gamma,
                                                const float* __restrict__ beta,
                                                float* __restrict__ bn_ac, float invN) {
    __shared__ float sd[4][64];
    int tid = threadIdx.x;
    int c = tid & 63, q = tid >> 6;
    float s = 0.f;
#pragma unroll
    for (int r = 0; r < 16; r++) s += partial2[(q * 16 + r) * 64 + c];
    sd[q][c] = s;
    __syncthreads();
    if (tid < 32) {
        float mu  = (sd[0][tid] + sd[1][tid] + sd[2][tid] + sd[3][tid]) * invN;
        float sq  = (sd[0][tid + 32] + sd[1][tid + 32] + sd[2][tid + 32] + sd[3][tid + 32]) * invN;
        float var = sq - mu * mu;
        float a = gamma[tid] * rsqrtf(var + 1e-5f);
        bn_ac[tid] = a;
        bn_ac[32 + tid] = beta[tid] - a * mu;
    }
}

// ---------- layer B: relu(bn(t)) @ W2 + b2, +relu, write packed bf16 ----------
__global__ __launch_bounds__(256) void layerB32_k(
    const float* __restrict__ tin, const float* __restrict__ bn_ac,
    const float* __restrict__ W2, const float* __restrict__ b2,
    unsigned* __restrict__ hout, int Nn)
{
    int tid = threadIdx.x;
    int j = tid & 31, grp = tid >> 5;
    float a = bn_ac[j], c = bn_ac[32 + j];
    float wc[32];
#pragma unroll
    for (int k = 0; k < 32; k++) wc[k] = W2[k * 32 + j];
    float bj = b2[j];
    for (int n = blockIdx.x * 8 + grp; n < Nn; n += gridDim.x * 8) {
        float t = tin[n * 32 + j];
        float u = fmaxf(fmaf(a, t, c), 0.f);
        float o = bj;
#pragma unroll
        for (int k = 0; k < 32; k++) o = fmaf(__shfl(u, k, 32), wc[k], o);
        unsigned b = bf16rne(fmaxf(o, 0.f));
        unsigned nb = (unsigned)__shfl_xor((int)b, 1, 32);
        if ((j & 1) == 0) hout[(unsigned)n * 16u + (unsigned)(j >> 1)] = b | (nb << 16);
    }
}

__global__ __launch_bounds__(256) void layerB64_k(
    const float* __restrict__ tin, const float* __restrict__ bn_ac,
    const float* __restrict__ W2, const float* __restrict__ b2,
    float* __restrict__ hout, int Nn)
{
    int tid = threadIdx.x;
    int j = tid & 31, grp = tid >> 5;
    float a = bn_ac[j], c = bn_ac[32 + j];
    float wlo[32], whi[32];
#pragma unroll
    for (int k = 0; k < 32; k++) { wlo[k] = W2[k * 64 + j]; whi[k] = W2[k * 64 + 32 + j]; }
    float blo = b2[j], bhi = b2[32 + j];
    for (int n = blockIdx.x * 8 + grp; n < Nn; n += gridDim.x * 8) {
        float t = tin[n * 32 + j];
        float u = fmaxf(fmaf(a, t, c), 0.f);
        float olo = blo, ohi = bhi;
#pragma unroll
        for (int k = 0; k < 32; k++) {
            float uk = __shfl(u, k, 32);
            olo = fmaf(uk, wlo[k], olo);
            ohi = fmaf(uk, whi[k], ohi);
        }
        hout[n * 64 + j] = olo;
        hout[n * 64 + 32 + j] = ohi;
    }
}

// ---------- pooling ----------
__global__ void pool1_k(const float* __restrict__ h5, const int* __restrict__ batch,
                        unsigned* __restrict__ maxb, float* __restrict__ sumb, int Nn)
{
    int ch = threadIdx.x & 63, slot = threadIdx.x >> 6;
    int base = blockIdx.x * 256 + slot * 64;
    int g = -1; float mx = 0.f, sm = 0.f;
    for (int i = 0; i < 64; i++) {
        int node = base + i;
        if (node >= Nn) break;
        int gn = batch[node];
        float v = h5[node * 64 + ch];
        if (gn != g) {
            if (g >= 0) { atomicMax(&maxb[g * 64 + ch], encf(mx)); atomicAdd(&sumb[g * 64 + ch], sm); }
            g = gn; mx = v; sm = v;
        } else { mx = fmaxf(mx, v); sm += v; }
    }
    if (g >= 0) { atomicMax(&maxb[g * 64 + ch], encf(mx)); atomicAdd(&sumb[g * 64 + ch], sm); }
}

__global__ void final_k(const unsigned* __restrict__ maxb, const float* __restrict__ sumb,
                        const int* __restrict__ batch, int Nn, float* __restrict__ out)
{
    int g = blockIdx.x, tid = threadIdx.x;
    int a = 0, b = Nn;
    while (a < b) { int m = (a + b) >> 1; if (batch[m] < g) a = m + 1; else b = m; }
    int lo0 = a;
    a = 0; b = Nn;
    while (a < b) { int m = (a + b) >> 1; if (batch[m] < g + 1) a = m + 1; else b = m; }
    int hi0 = a;
    float inv = 1.f / fmaxf((float)(hi0 - lo0), 1.f);
    if (tid < 64) out[g * 128 + tid] = decf(maxb[g * 64 + tid]);
    else          out[g * 128 + tid] = sumb[g * 64 + (tid - 64)] * inv;
}

extern "C" void kernel_launch(void* const* d_in, const int* in_sizes, int n_in,
                              void* d_out, int out_size, void* d_ws, size_t ws_size,
                              hipStream_t stream) {
    const float* x    = (const float*)d_in[0];
    const int*   ei   = (const int*)d_in[1];
    const int*   ety  = (const int*)d_in[2];
    const int*   batch= (const int*)d_in[3];
    const float* emb  = (const float*)d_in[4];
    const float* W1s  = (const float*)d_in[5];
    const float* b1s  = (const float*)d_in[6];
    const float* g1s  = (const float*)d_in[7];
    const float* be1s = (const float*)d_in[8];
    const float* W2s  = (const float*)d_in[9];
    const float* b2s  = (const float*)d_in[10];
    const float* w15  = (const float*)d_in[11];
    const float* b15  = (const float*)d_in[12];
    const float* g5   = (const float*)d_in[13];
    const float* be5  = (const float*)d_in[14];
    const float* w25  = (const float*)d_in[15];
    const float* b25  = (const float*)d_in[16];

    int N = in_sizes[0] / 32;
    int E = in_sizes[1] / 2;
    int G = out_size / 128;

    int sBits = 1; while ((1 << sBits) < N + 1) sBits++;            // 18
    int bshift = 0; while (((N - 1) >> bshift) >= 512) bshift++;    // 9
    int nb2 = ((N - 1) >> bshift) + 1;                              // 391
    int nblkE = (E + 4095) / 4096;                                  // 977

    char* wsb = (char*)d_ws;
    size_t o = 0;
    size_t hPkBytes = (size_t)(N + 1) * 16 * 4;
    size_t tbBytes = (size_t)N * 32 * 4;
    size_t binBytes = (size_t)E * 4;
    size_t rtb = tbBytes > binBytes ? tbBytes : binBytes;
    unsigned* P      = (unsigned*)(wsb + o); o += hPkBytes;
    unsigned* Q      = (unsigned*)(wsb + o); o += hPkBytes;
    float*    tb     = (float*)(wsb + o);
    unsigned* binned = (unsigned*)(wsb + o);        // alias: dead before layerA L0
    o += rtb;
    float*    h5w    = (float*)(wsb + o); o += (size_t)N * 64 * 4;
    int*      rowptr = (int*)(wsb + o);   o += ((size_t)N + 2) * 4;
    unsigned* sorted = (unsigned*)(wsb + o); o += (size_t)E * 4;
    int*      chunkTot = (int*)(wsb + o); o += 1024;
    int*      chunkOff = (int*)(wsb + o); o += 1024;
    float*    partial  = (float*)(wsb + o); o += (size_t)NBLKA * 64 * 4;
    float*    partial2 = (float*)(wsb + o); o += 64 * 64 * 4;
    float*    bn_ac    = (float*)(wsb + o); o += 64 * 4;
    unsigned* maxb     = (unsigned*)(wsb + o); o += (size_t)G * 64 * 4;
    float*    sumb     = (float*)(wsb + o); o += (size_t)G * 64 * 4;
    int*      cntMat   = (int*)(wsb + o); o += (size_t)nb2 * nblkE * 4;

    // ---- CSR build ----
    passA_k<<<nblkE, 256, 0, stream>>>(ei + E, E, cntMat, bshift, nblkE, nb2);
    int total2 = nb2 * nblkE;
    int nchunk2 = (total2 + 2047) / 2048;
    scanA_k<<<nchunk2, 256, 0, stream>>>(cntMat, total2, chunkTot);
    scanB_k<<<1, 256, 0, stream>>>(chunkTot, nchunk2, chunkOff);
    scanC2_k<<<nchunk2, 256, 0, stream>>>(cntMat, total2, chunkOff);
    passB_k<<<nblkE, 256, 0, stream>>>(ei, ety, E, cntMat, binned, bshift, sBits, nblkE, nb2);
    passC_k<<<nb2, 256, 0, stream>>>(binned, cntMat, nblkE, rowptr, sorted, N, E, bshift, sBits, nb2);
    copyx_k<<<(N * 16 + 255) / 256, 256, 0, stream>>>(x, P, Q, N);
    initpool_k<<<(G * 64 + 255) / 256, 256, 0, stream>>>(maxb, sumb, G * 64);

    unsigned sentw = (unsigned)N;

    // ---- 5 GINE layers (ping-pong P<->Q, t via f32 tb) ----
    unsigned* inb = P;
    unsigned* outb = Q;
    for (int L = 0; L < 5; ++L) {
        const float* W1 = (L < 4) ? W1s + L * 1024 : w15;
        const float* b1 = (L < 4) ? b1s + L * 32  : b15;
        const float* ga = (L < 4) ? g1s + L * 32  : g5;
        const float* be = (L < 4) ? be1s + L * 32 : be5;
        const float* W2 = (L < 4) ? W2s + L * 1024 : w25;
        const float* b2 = (L < 4) ? b2s + L * 32  : b25;

        layerA_k<<<NBLKA, 256, 0, stream>>>(inb, rowptr, sorted, emb, W1, b1, tb, partial, N, sBits, sentw);
        bnred1_k<<<64, 256, 0, stream>>>(partial, partial2);
        bnred2_k<<<1, 256, 0, stream>>>(partial2, ga, be, bn_ac, 1.f / (float)N);
        if (L < 4) {
            layerB32_k<<<1024, 256, 0, stream>>>(tb, bn_ac, W2, b2, outb, N);
            unsigned* tmp = inb; inb = outb; outb = tmp;
        } else {
            layerB64_k<<<1024, 256, 0, stream>>>(tb, bn_ac, W2, b2, h5w, N);
        }
    }

    // ---- pooling ----
    pool1_k<<<(N + 255) / 256, 256, 0, stream>>>(h5w, batch, maxb, sumb, N);
    final_k<<<G, 128, 0, stream>>>(maxb, sumb, batch, N, (float*)d_out);
}

// Round 9
// 700.115 us; speedup vs baseline: 1.5501x; 1.5501x over previous
//
#include <hip/hip_runtime.h>

#define NBLKA 2048

__device__ __forceinline__ unsigned encf(float x) {
    unsigned u = __float_as_uint(x);
    return (u & 0x80000000u) ? ~u : (u | 0x80000000u);
}
__device__ __forceinline__ float decf(unsigned u) {
    u = (u & 0x80000000u) ? (u & 0x7FFFFFFFu) : ~u;
    return __uint_as_float(u);
}
__device__ __forceinline__ unsigned bf16rne(float f) {
    unsigned u = __float_as_uint(f);
    return (u + 0x7FFFu + ((u >> 16) & 1u)) >> 16;
}

// ============ CSR build: 512-node buckets, deterministic matrix scan ============

__global__ __launch_bounds__(256) void passA_k(const int* __restrict__ dst, int E,
                                               int* __restrict__ cntMat, int bshift,
                                               int nblk, int nb2) {
    __shared__ int hist[512];
    hist[threadIdx.x] = 0; hist[threadIdx.x + 256] = 0;
    __syncthreads();
    int base = blockIdx.x * 4096;
#pragma unroll
    for (int r = 0; r < 16; r++) {
        int i = base + threadIdx.x + r * 256;
        if (i < E) atomicAdd(&hist[dst[i] >> bshift], 1);
    }
    __syncthreads();
    for (int bk = threadIdx.x; bk < nb2; bk += 256)
        cntMat[bk * nblk + blockIdx.x] = hist[bk];
}

__global__ void scanA_k(int* __restrict__ data, int total, int* __restrict__ chunkTot) {
    __shared__ int sd[256];
    int tid = threadIdx.x;
    int base = blockIdx.x * 2048 + tid * 8;
    int v[8]; int s = 0;
#pragma unroll
    for (int r = 0; r < 8; r++) {
        int idx = base + r;
        int x = (idx < total) ? data[idx] : 0;
        s += x; v[r] = s;
    }
    sd[tid] = s; __syncthreads();
    for (int off = 1; off < 256; off <<= 1) {
        int x = (tid >= off) ? sd[tid - off] : 0;
        __syncthreads();
        sd[tid] += x;
        __syncthreads();
    }
    int prev = (tid > 0) ? sd[tid - 1] : 0;
#pragma unroll
    for (int r = 0; r < 8; r++) {
        int idx = base + r;
        if (idx < total) data[idx] = v[r] + prev;
    }
    if (tid == 255) chunkTot[blockIdx.x] = sd[255];
}

__global__ void scanB_k(const int* __restrict__ chunkTot, int nchunk, int* __restrict__ chunkOff) {
    __shared__ int sd[256];
    int tid = threadIdx.x;
    int v = (tid < nchunk) ? chunkTot[tid] : 0;
    sd[tid] = v; __syncthreads();
    for (int off = 1; off < 256; off <<= 1) {
        int x = (tid >= off) ? sd[tid - off] : 0;
        __syncthreads();
        sd[tid] += x;
        __syncthreads();
    }
    if (tid < nchunk) chunkOff[tid] = sd[tid] - v;
}

__global__ void scanC2_k(int* __restrict__ data, int total, const int* __restrict__ chunkOff) {
    int off = chunkOff[blockIdx.x];
    int base = blockIdx.x * 2048 + threadIdx.x * 8;
#pragma unroll
    for (int r = 0; r < 8; r++) {
        int idx = base + r;
        if (idx < total) data[idx] += off;
    }
}

__global__ __launch_bounds__(256) void passB_k(const int* __restrict__ ei,
                                               const int* __restrict__ ety, int E,
                                               const int* __restrict__ cntScan,
                                               unsigned* __restrict__ binned,
                                               int bshift, int sBits, int nblk, int nb2) {
    __shared__ unsigned stage[4096];
    __shared__ unsigned short bkid[4096];
    __shared__ int hist[512], sd[256], cursor[512], rebase[512];
    int tid = threadIdx.x;
    int base = blockIdx.x * 4096;
    hist[tid] = 0; hist[tid + 256] = 0;
    __syncthreads();

    unsigned ent[16];
    int bk[16];
    int lowmask = (1 << bshift) - 1;
    int dshift = sBits + 1;
#pragma unroll
    for (int r = 0; r < 16; r++) {
        int i = base + tid + r * 256;
        if (i < E) {
            int s = ei[i];
            int d = ei[E + i];
            int t = ety[i];
            ent[r] = ((unsigned)(d & lowmask) << dshift) | ((unsigned)t << sBits) | (unsigned)s;
            bk[r] = d >> bshift;
            atomicAdd(&hist[bk[r]], 1);
        } else bk[r] = -1;
    }
    __syncthreads();

    int v0 = hist[2 * tid], v1 = hist[2 * tid + 1];
    int sum2 = v0 + v1;
    sd[tid] = sum2; __syncthreads();
    for (int off = 1; off < 256; off <<= 1) {
        int x = (tid >= off) ? sd[tid - off] : 0;
        __syncthreads();
        sd[tid] += x;
        __syncthreads();
    }
    int exclPair = sd[tid] - sum2;
    __syncthreads();
    cursor[2 * tid] = exclPair;
    cursor[2 * tid + 1] = exclPair + v0;
    int b0 = 2 * tid, b1 = 2 * tid + 1;
    rebase[b0] = (b0 < nb2 && v0 > 0) ? (cntScan[b0 * nblk + blockIdx.x] - v0) - exclPair : 0;
    rebase[b1] = (b1 < nb2 && v1 > 0) ? (cntScan[b1 * nblk + blockIdx.x] - v1) - (exclPair + v0) : 0;
    __syncthreads();

#pragma unroll
    for (int r = 0; r < 16; r++) {
        if (bk[r] >= 0) {
            int p = atomicAdd(&cursor[bk[r]], 1);
            stage[p] = ent[r];
            bkid[p] = (unsigned short)bk[r];
        }
    }
    __syncthreads();

    int cnt = E - base; if (cnt > 4096) cnt = 4096;
    for (int i = tid; i < cnt; i += 256)
        binned[rebase[bkid[i]] + i] = stage[i];
}

__global__ __launch_bounds__(256) void passC_k(const unsigned* __restrict__ binned,
                                               const int* __restrict__ cntScan,
                                               int nblk, int* __restrict__ rowptr,
                                               unsigned* __restrict__ sorted,
                                               int N, int E, int bshift, int sBits,
                                               int nb2) {
    __shared__ int hist[512], cursor[512], sd[256];
    int tid = threadIdx.x;
    int b = blockIdx.x;
    int s = (b == 0) ? 0 : cntScan[b * nblk - 1];
    int e = cntScan[(b + 1) * nblk - 1];
    int nodeBase = b << bshift;
    int dshift = sBits + 1;

    hist[tid] = 0; hist[tid + 256] = 0;
    __syncthreads();
    for (int i = s + tid; i < e; i += 256)
        atomicAdd(&hist[(int)(binned[i] >> dshift)], 1);
    __syncthreads();

    int v0 = hist[2 * tid], v1 = hist[2 * tid + 1];
    int sum2 = v0 + v1;
    sd[tid] = sum2; __syncthreads();
    for (int off = 1; off < 256; off <<= 1) {
        int x = (tid >= off) ? sd[tid - off] : 0;
        __syncthreads();
        sd[tid] += x;
        __syncthreads();
    }
    int exclPair = sd[tid] - sum2;
    __syncthreads();
    cursor[2 * tid] = exclPair;
    cursor[2 * tid + 1] = exclPair + v0;
    int n0 = nodeBase + 2 * tid, n1 = nodeBase + 2 * tid + 1;
    if (n0 < N) rowptr[n0] = s + exclPair;
    if (n1 < N) rowptr[n1] = s + exclPair + v0;
    __syncthreads();

    for (int i = s + tid; i < e; i += 256) {
        unsigned en = binned[i];
        int ln = (int)(en >> dshift);
        int p = atomicAdd(&cursor[ln], 1);
        sorted[s + p] = en;
    }
    if (b == nb2 - 1 && tid == 0) rowptr[N] = E;
}

__global__ void initpool_k(unsigned* __restrict__ maxb, float* __restrict__ sumb, int n) {
    int i = blockIdx.x * blockDim.x + threadIdx.x;
    if (i < n) { maxb[i] = 0x007FFFFFu; sumb[i] = 0.f; }
}

// copy x -> packed bf16 pairs in P; set sentinel rows of P and Q
__global__ void copyx_k(const float* __restrict__ x, unsigned* __restrict__ P,
                        unsigned* __restrict__ Q, int N) {
    int i = blockIdx.x * 256 + threadIdx.x;
    int tot = N * 16;
    if (i < tot) {
        float2 v = ((const float2*)x)[i];
        P[i] = bf16rne(v.x) | (bf16rne(v.y) << 16);
    }
    if (i < 16) {
        unsigned sp = bf16rne(-1e30f) | (bf16rne(-1e30f) << 16);
        P[tot + i] = sp;
        Q[tot + i] = sp;
    }
}

// ---------- layer A (round-7 proven body): 16 ch-lanes x 2 edge slots, bf16 h ----------
__global__ __launch_bounds__(256) void layerA_k(
    const unsigned* __restrict__ hin, const int* __restrict__ rowptr,
    const unsigned* __restrict__ sorted, const float* __restrict__ emb,
    const float* __restrict__ W1, const float* __restrict__ b1,
    float* __restrict__ tout, float* __restrict__ partial, int Nn, int sBits,
    unsigned sentw)
{
    float2* tout2 = (float2*)tout;
    int tid = threadIdx.x;
    int gl = tid & 31;
    int c = gl & 15;            // channel-pair index
    int slot = gl >> 4;         // edge slot / k-half
    int grp = tid >> 5;
    unsigned smask = (1u << sBits) - 1u;

    float2 w1c[16];
#pragma unroll
    for (int kk = 0; kk < 16; kk++)
        w1c[kk] = *(const float2*)&W1[(16 * slot + kk) * 32 + 2 * c];
    float2 b1p = *(const float2*)&b1[2 * c];
    float2 e0p = *(const float2*)&emb[2 * c];
    float2 e1p = *(const float2*)&emb[32 + 2 * c];

    __shared__ float zl[8][32];
    __shared__ float ls[8][32], lq[8][32];

    float2 bsum = {0.f, 0.f}, bsq = {0.f, 0.f};

    int gid0 = (blockIdx.x * 256 + tid) >> 5;
    int nG = (gridDim.x * 256) >> 5;

    for (int n = gid0; n < Nn; n += nG) {
        int es = rowptr[n], ee = rowptr[n + 1];
        float accx = 0.f, accy = 0.f;
        for (int e0 = es; e0 < ee; e0 += 32) {
            int idx = e0 + gl;
            unsigned pv = (idx < ee) ? sorted[idx] : sentw;
#pragma unroll
            for (int kk = 0; kk < 16; kk++) {
                unsigned p = (unsigned)__shfl((int)pv, kk, 16);
                unsigned s = p & smask;
                unsigned w = hin[s * 16u + (unsigned)c];
                float hx = __uint_as_float(w << 16);
                float hy = __uint_as_float(w & 0xFFFF0000u);
                bool t1 = ((p >> sBits) & 1u) != 0u;
                float evx = t1 ? e1p.x : e0p.x;
                float evy = t1 ? e1p.y : e0p.y;
                accx += fmaxf(hx + evx, 0.f);
                accy += fmaxf(hy + evy, 0.f);
            }
        }
        accx += __shfl_xor(accx, 16);
        accy += __shfl_xor(accy, 16);
        unsigned wn = hin[(unsigned)n * 16u + (unsigned)c];
        accx += __uint_as_float(wn << 16);
        accy += __uint_as_float(wn & 0xFFFF0000u);

        if (slot == 0) { zl[grp][2 * c] = accx; zl[grp][2 * c + 1] = accy; }
        float tx = 0.f, ty = 0.f;
#pragma unroll
        for (int kk = 0; kk < 16; kk++) {
            float zk = zl[grp][16 * slot + kk];
            tx = fmaf(zk, w1c[kk].x, tx);
            ty = fmaf(zk, w1c[kk].y, ty);
        }
        tx += __shfl_xor(tx, 16);
        ty += __shfl_xor(ty, 16);
        tx += b1p.x; ty += b1p.y;
        if (slot == 0) { float2 tp; tp.x = tx; tp.y = ty; tout2[(unsigned)n * 16u + (unsigned)c] = tp; }
        bsum.x += tx; bsum.y += ty;
        bsq.x = fmaf(tx, tx, bsq.x);
        bsq.y = fmaf(ty, ty, bsq.y);
    }

    if (slot == 0) {
        ls[grp][2 * c] = bsum.x; ls[grp][2 * c + 1] = bsum.y;
        lq[grp][2 * c] = bsq.x;  lq[grp][2 * c + 1] = bsq.y;
    }
    __syncthreads();
    if (tid < 32) {
        float s = 0.f, q = 0.f;
#pragma unroll
        for (int r = 0; r < 8; r++) { s += ls[r][tid]; q += lq[r][tid]; }
        partial[blockIdx.x * 64 + tid] = s;
        partial[blockIdx.x * 64 + 32 + tid] = q;
    }
}

// ---------- BN stat reduce, two-stage parallel ----------
__global__ __launch_bounds__(256) void bnred1_k(const float* __restrict__ partial,
                                                float* __restrict__ partial2) {
    __shared__ float sd[4][64];
    int tid = threadIdx.x;
    int c = tid & 63, q = tid >> 6;
    int rowBase = blockIdx.x * 32 + q * 8;
    float s = 0.f;
#pragma unroll
    for (int r = 0; r < 8; r++) s += partial[(rowBase + r) * 64 + c];
    sd[q][c] = s;
    __syncthreads();
    if (q == 0) partial2[blockIdx.x * 64 + c] = sd[0][c] + sd[1][c] + sd[2][c] + sd[3][c];
}

__global__ __launch_bounds__(256) void bnred2_k(const float* __restrict__ partial2,
                                                const float* __restrict__ gamma,
                                                const float* __restrict__ beta,
                                                float* __restrict__ bn_ac, float invN) {
    __shared__ float sd[4][64];
    int tid = threadIdx.x;
    int c = tid & 63, q = tid >> 6;
    float s = 0.f;
#pragma unroll
    for (int r = 0; r < 16; r++) s += partial2[(q * 16 + r) * 64 + c];
    sd[q][c] = s;
    __syncthreads();
    if (tid < 32) {
        float mu  = (sd[0][tid] + sd[1][tid] + sd[2][tid] + sd[3][tid]) * invN;
        float sq  = (sd[0][tid + 32] + sd[1][tid + 32] + sd[2][tid + 32] + sd[3][tid + 32]) * invN;
        float var = sq - mu * mu;
        float a = gamma[tid] * rsqrtf(var + 1e-5f);
        bn_ac[tid] = a;
        bn_ac[32 + tid] = beta[tid] - a * mu;
    }
}

// ---------- layer B: relu(bn(t)) @ W2 + b2, +relu, write packed bf16 ----------
__global__ __launch_bounds__(256) void layerB32_k(
    const float* __restrict__ tin, const float* __restrict__ bn_ac,
    const float* __restrict__ W2, const float* __restrict__ b2,
    unsigned* __restrict__ hout, int Nn)
{
    int tid = threadIdx.x;
    int j = tid & 31, grp = tid >> 5;
    float a = bn_ac[j], c = bn_ac[32 + j];
    float wc[32];
#pragma unroll
    for (int k = 0; k < 32; k++) wc[k] = W2[k * 32 + j];
    float bj = b2[j];
    for (int n = blockIdx.x * 8 + grp; n < Nn; n += gridDim.x * 8) {
        float t = tin[n * 32 + j];
        float u = fmaxf(fmaf(a, t, c), 0.f);
        float o = bj;
#pragma unroll
        for (int k = 0; k < 32; k++) o = fmaf(__shfl(u, k, 32), wc[k], o);
        unsigned b = bf16rne(fmaxf(o, 0.f));
        unsigned nb = (unsigned)__shfl_xor((int)b, 1, 32);
        if ((j & 1) == 0) hout[(unsigned)n * 16u + (unsigned)(j >> 1)] = b | (nb << 16);
    }
}

__global__ __launch_bounds__(256) void layerB64_k(
    const float* __restrict__ tin, const float* __restrict__ bn_ac,
    const float* __restrict__ W2, const float* __restrict__ b2,
    float* __restrict__ hout, int Nn)
{
    int tid = threadIdx.x;
    int j = tid & 31, grp = tid >> 5;
    float a = bn_ac[j], c = bn_ac[32 + j];
    float wlo[32], whi[32];
#pragma unroll
    for (int k = 0; k < 32; k++) { wlo[k] = W2[k * 64 + j]; whi[k] = W2[k * 64 + 32 + j]; }
    float blo = b2[j], bhi = b2[32 + j];
    for (int n = blockIdx.x * 8 + grp; n < Nn; n += gridDim.x * 8) {
        float t = tin[n * 32 + j];
        float u = fmaxf(fmaf(a, t, c), 0.f);
        float olo = blo, ohi = bhi;
#pragma unroll
        for (int k = 0; k < 32; k++) {
            float uk = __shfl(u, k, 32);
            olo = fmaf(uk, wlo[k], olo);
            ohi = fmaf(uk, whi[k], ohi);
        }
        hout[n * 64 + j] = olo;
        hout[n * 64 + 32 + j] = ohi;
    }
}

// ---------- pooling ----------
__global__ void pool1_k(const float* __restrict__ h5, const int* __restrict__ batch,
                        unsigned* __restrict__ maxb, float* __restrict__ sumb, int Nn)
{
    int ch = threadIdx.x & 63, slot = threadIdx.x >> 6;
    int base = blockIdx.x * 256 + slot * 64;
    int g = -1; float mx = 0.f, sm = 0.f;
    for (int i = 0; i < 64; i++) {
        int node = base + i;
        if (node >= Nn) break;
        int gn = batch[node];
        float v = h5[node * 64 + ch];
        if (gn != g) {
            if (g >= 0) { atomicMax(&maxb[g * 64 + ch], encf(mx)); atomicAdd(&sumb[g * 64 + ch], sm); }
            g = gn; mx = v; sm = v;
        } else { mx = fmaxf(mx, v); sm += v; }
    }
    if (g >= 0) { atomicMax(&maxb[g * 64 + ch], encf(mx)); atomicAdd(&sumb[g * 64 + ch], sm); }
}

__global__ void final_k(const unsigned* __restrict__ maxb, const float* __restrict__ sumb,
                        const int* __restrict__ batch, int Nn, float* __restrict__ out)
{
    int g = blockIdx.x, tid = threadIdx.x;
    int a = 0, b = Nn;
    while (a < b) { int m = (a + b) >> 1; if (batch[m] < g) a = m + 1; else b = m; }
    int lo0 = a;
    a = 0; b = Nn;
    while (a < b) { int m = (a + b) >> 1; if (batch[m] < g + 1) a = m + 1; else b = m; }
    int hi0 = a;
    float inv = 1.f / fmaxf((float)(hi0 - lo0), 1.f);
    if (tid < 64) out[g * 128 + tid] = decf(maxb[g * 64 + tid]);
    else          out[g * 128 + tid] = sumb[g * 64 + (tid - 64)] * inv;
}

extern "C" void kernel_launch(void* const* d_in, const int* in_sizes, int n_in,
                              void* d_out, int out_size, void* d_ws, size_t ws_size,
                              hipStream_t stream) {
    const float* x    = (const float*)d_in[0];
    const int*   ei   = (const int*)d_in[1];
    const int*   ety  = (const int*)d_in[2];
    const int*   batch= (const int*)d_in[3];
    const float* emb  = (const float*)d_in[4];
    const float* W1s  = (const float*)d_in[5];
    const float* b1s  = (const float*)d_in[6];
    const float* g1s  = (const float*)d_in[7];
    const float* be1s = (const float*)d_in[8];
    const float* W2s  = (const float*)d_in[9];
    const float* b2s  = (const float*)d_in[10];
    const float* w15  = (const float*)d_in[11];
    const float* b15  = (const float*)d_in[12];
    const float* g5   = (const float*)d_in[13];
    const float* be5  = (const float*)d_in[14];
    const float* w25  = (const float*)d_in[15];
    const float* b25  = (const float*)d_in[16];

    int N = in_sizes[0] / 32;
    int E = in_sizes[1] / 2;
    int G = out_size / 128;

    int sBits = 1; while ((1 << sBits) < N + 1) sBits++;            // 18
    int bshift = 0; while (((N - 1) >> bshift) >= 512) bshift++;    // 9
    int nb2 = ((N - 1) >> bshift) + 1;                              // 391
    int nblkE = (E + 4095) / 4096;                                  // 977

    char* wsb = (char*)d_ws;
    size_t o = 0;
    size_t hPkBytes = (size_t)(N + 1) * 16 * 4;
    size_t tbBytes = (size_t)N * 32 * 4;
    size_t binBytes = (size_t)E * 4;
    size_t rtb = tbBytes > binBytes ? tbBytes : binBytes;
    unsigned* P      = (unsigned*)(wsb + o); o += hPkBytes;
    unsigned* Q      = (unsigned*)(wsb + o); o += hPkBytes;
    float*    tb     = (float*)(wsb + o);
    unsigned* binned = (unsigned*)(wsb + o);        // alias: dead before layerA L0
    o += rtb;
    float*    h5w    = (float*)(wsb + o); o += (size_t)N * 64 * 4;
    int*      rowptr = (int*)(wsb + o);   o += ((size_t)N + 2) * 4;
    unsigned* sorted = (unsigned*)(wsb + o); o += (size_t)E * 4;
    int*      chunkTot = (int*)(wsb + o); o += 1024;
    int*      chunkOff = (int*)(wsb + o); o += 1024;
    float*    partial  = (float*)(wsb + o); o += (size_t)NBLKA * 64 * 4;
    float*    partial2 = (float*)(wsb + o); o += 64 * 64 * 4;
    float*    bn_ac    = (float*)(wsb + o); o += 64 * 4;
    unsigned* maxb     = (unsigned*)(wsb + o); o += (size_t)G * 64 * 4;
    float*    sumb     = (float*)(wsb + o); o += (size_t)G * 64 * 4;
    int*      cntMat   = (int*)(wsb + o); o += (size_t)nb2 * nblkE * 4;

    // ---- CSR build ----
    passA_k<<<nblkE, 256, 0, stream>>>(ei + E, E, cntMat, bshift, nblkE, nb2);
    int total2 = nb2 * nblkE;
    int nchunk2 = (total2 + 2047) / 2048;
    scanA_k<<<nchunk2, 256, 0, stream>>>(cntMat, total2, chunkTot);
    scanB_k<<<1, 256, 0, stream>>>(chunkTot, nchunk2, chunkOff);
    scanC2_k<<<nchunk2, 256, 0, stream>>>(cntMat, total2, chunkOff);
    passB_k<<<nblkE, 256, 0, stream>>>(ei, ety, E, cntMat, binned, bshift, sBits, nblkE, nb2);
    passC_k<<<nb2, 256, 0, stream>>>(binned, cntMat, nblkE, rowptr, sorted, N, E, bshift, sBits, nb2);
    copyx_k<<<(N * 16 + 255) / 256, 256, 0, stream>>>(x, P, Q, N);
    initpool_k<<<(G * 64 + 255) / 256, 256, 0, stream>>>(maxb, sumb, G * 64);

    unsigned sentw = (unsigned)N;

    // ---- 5 GINE layers (ping-pong P<->Q, t via f32 tb) ----
    unsigned* inb = P;
    unsigned* outb = Q;
    for (int L = 0; L < 5; ++L) {
        const float* W1 = (L < 4) ? W1s + L * 1024 : w15;
        const float* b1 = (L < 4) ? b1s + L * 32  : b15;
        const float* ga = (L < 4) ? g1s + L * 32  : g5;
        const float* be = (L < 4) ? be1s + L * 32 : be5;
        const float* W2 = (L < 4) ? W2s + L * 1024 : w25;
        const float* b2 = (L < 4) ? b2s + L * 32  : b25;

        layerA_k<<<NBLKA, 256, 0, stream>>>(inb, rowptr, sorted, emb, W1, b1, tb, partial, N, sBits, sentw);
        bnred1_k<<<64, 256, 0, stream>>>(partial, partial2);
        bnred2_k<<<1, 256, 0, stream>>>(partial2, ga, be, bn_ac, 1.f / (float)N);
        if (L < 4) {
            layerB32_k<<<1024, 256, 0, stream>>>(tb, bn_ac, W2, b2, outb, N);
            unsigned* tmp = inb; inb = outb; outb = tmp;
        } else {
            layerB64_k<<<1024, 256, 0, stream>>>(tb, bn_ac, W2, b2, h5w, N);
        }
    }

    // ---- pooling ----
    pool1_k<<<(N + 255) / 256, 256, 0, stream>>>(h5w, batch, maxb, sumb, N);
    final_k<<<G, 128, 0, stream>>>(maxb, sumb, batch, N, (float*)d_out);
}